// Round 1
// baseline (705.541 us; speedup 1.0000x reference)
//
#include <hip/hip_runtime.h>

// GCN 2-layer: transform-first + CSR-by-dst gather aggregation (no f32 atomics
// in hot loops). Pipeline:
//   memset counters -> degrees (atomic) -> prefix-scan deg_in -> norms ->
//   bucket edges by dst (counting sort, reused by BOTH layers) ->
//   GEMM1 xt = norm_out*(x@W1) -> AGG1 h1 = relu(norm_in*segsum(xt[src]) + b1) ->
//   GEMM2 h1t = norm_out*(h1@W2) [30 cols padded to 32] ->
//   AGG2 out = norm_in*segsum(h1t[src]) + b2
// Math identity used: segsum(h[src]) @ W == segsum((h@W)[src]); per-row scales
// commute with the right-multiply. Layer-2 gather shrinks 64 -> 32 features.

#define NN 100000
#define NE 3200000
#define HID 64
#define NOUTF 30

#define TPB 256
#define SCAN_CHUNK 1024
#define NSCAN ((NN + SCAN_CHUNK - 1) / SCAN_CHUNK)  // 98

// ---------------- degrees ----------------
__global__ __launch_bounds__(TPB) void k_deg(const int* __restrict__ src,
                                             const int* __restrict__ dst,
                                             int* __restrict__ deg_out,
                                             int* __restrict__ deg_in) {
  int e = blockIdx.x * TPB + threadIdx.x;
  if (e < NE) {
    atomicAdd(&deg_out[src[e]], 1);
    atomicAdd(&deg_in[dst[e]], 1);
  }
}

// ---------------- prefix scan of deg_in -> row_ptr (3 kernels) ----------------
__global__ __launch_bounds__(TPB) void k_scan1(const int* __restrict__ deg,
                                               int* __restrict__ bsums) {
  int t = threadIdx.x;
  int base = blockIdx.x * SCAN_CHUNK;
  int s = 0;
  for (int i = t; i < SCAN_CHUNK; i += TPB) {
    int idx = base + i;
    if (idx < NN) s += deg[idx];
  }
  __shared__ int red[TPB];
  red[t] = s;
  __syncthreads();
  for (int off = TPB / 2; off > 0; off >>= 1) {
    if (t < off) red[t] += red[t + off];
    __syncthreads();
  }
  if (t == 0) bsums[blockIdx.x] = red[0];
}

__global__ __launch_bounds__(128) void k_scan2(int* __restrict__ bsums) {
  int t = threadIdx.x;
  __shared__ int lds[128];
  int v = (t < NSCAN) ? bsums[t] : 0;
  int acc = v;
  lds[t] = acc;
  __syncthreads();
  for (int off = 1; off < 128; off <<= 1) {
    int add = (t >= off) ? lds[t - off] : 0;
    __syncthreads();
    acc += add;
    lds[t] = acc;
    __syncthreads();
  }
  if (t < NSCAN) bsums[t] = acc - v;  // exclusive block offsets
}

__global__ __launch_bounds__(TPB) void k_scan3(const int* __restrict__ deg,
                                               const int* __restrict__ bsums,
                                               int* __restrict__ row_ptr) {
  int t = threadIdx.x;
  int base = blockIdx.x * SCAN_CHUNK + t * 4;
  int v[4];
  int s = 0;
#pragma unroll
  for (int j = 0; j < 4; ++j) {
    int idx = base + j;
    v[j] = (idx < NN) ? deg[idx] : 0;
    s += v[j];
  }
  __shared__ int lds[TPB];
  int acc = s;
  lds[t] = acc;
  __syncthreads();
  for (int off = 1; off < TPB; off <<= 1) {
    int add = (t >= off) ? lds[t - off] : 0;
    __syncthreads();
    acc += add;
    lds[t] = acc;
    __syncthreads();
  }
  int run = bsums[blockIdx.x] + (acc - s);
#pragma unroll
  for (int j = 0; j < 4; ++j) {
    int idx = base + j;
    if (idx < NN) row_ptr[idx] = run;
    run += v[j];
  }
  if (blockIdx.x == 0 && t == 0) row_ptr[NN] = NE;  // total in-degree == NE
}

// ---------------- norms ----------------
__global__ __launch_bounds__(TPB) void k_norm(const int* __restrict__ deg_out,
                                              const int* __restrict__ deg_in,
                                              float* __restrict__ norm_out,
                                              float* __restrict__ norm_in) {
  int i = blockIdx.x * TPB + threadIdx.x;
  if (i < NN) {
    int d0 = deg_out[i], d1 = deg_in[i];
    norm_out[i] = (d0 > 0) ? rsqrtf((float)d0) : 0.0f;
    norm_in[i] = (d1 > 0) ? rsqrtf((float)d1) : 0.0f;
  }
}

// ---------------- bucket edges by dst (counting sort) ----------------
__global__ __launch_bounds__(TPB) void k_bucket(const int* __restrict__ src,
                                                const int* __restrict__ dst,
                                                const int* __restrict__ row_ptr,
                                                int* __restrict__ cursor,
                                                int* __restrict__ src_sorted) {
  int e = blockIdx.x * TPB + threadIdx.x;
  if (e < NE) {
    int d = dst[e];
    int p = row_ptr[d] + atomicAdd(&cursor[d], 1);
    src_sorted[p] = src[e];
  }
}

// ---------------- GEMM1: xt[n] = norm_out[n] * (x[n] @ W1)  [64 -> 64] -------
// Wave processes 4 nodes/iter. Lane g holds W1[:,g] in 64 VGPRs (loaded
// coalesced once). 4 node-rows live in the wave's registers as float4 slices;
// row elements broadcast via v_readlane (no LDS at all).
__global__ __launch_bounds__(TPB) void k_gemm1(const float4* __restrict__ x4,
                                               const float* __restrict__ W1,
                                               const float* __restrict__ norm_out,
                                               float* __restrict__ xt) {
  int lane = threadIdx.x & 63;
  int wid = (blockIdx.x * TPB + threadIdx.x) >> 6;
  int nwaves = gridDim.x * (TPB / 64);
  float w[64];
#pragma unroll
  for (int k = 0; k < 64; ++k) w[k] = W1[k * 64 + lane];  // coalesced row reads
  int m = lane >> 4, q = lane & 15;
  for (int grp = wid; grp < NN / 4; grp += nwaves) {
    int nbase = grp * 4;
    float4 rv = x4[(nbase + m) * 16 + q];  // 1KB fully-coalesced: 4 rows
    int r0 = __float_as_int(rv.x), r1 = __float_as_int(rv.y);
    int r2 = __float_as_int(rv.z), r3 = __float_as_int(rv.w);
    float acc[4] = {0.f, 0.f, 0.f, 0.f};
#pragma unroll
    for (int mm = 0; mm < 4; ++mm) {
#pragma unroll
      for (int ql = 0; ql < 16; ++ql) {
        int sl = mm * 16 + ql;
        acc[mm] = fmaf(__int_as_float(__builtin_amdgcn_readlane(r0, sl)), w[ql * 4 + 0], acc[mm]);
        acc[mm] = fmaf(__int_as_float(__builtin_amdgcn_readlane(r1, sl)), w[ql * 4 + 1], acc[mm]);
        acc[mm] = fmaf(__int_as_float(__builtin_amdgcn_readlane(r2, sl)), w[ql * 4 + 2], acc[mm]);
        acc[mm] = fmaf(__int_as_float(__builtin_amdgcn_readlane(r3, sl)), w[ql * 4 + 3], acc[mm]);
      }
    }
#pragma unroll
    for (int mm = 0; mm < 4; ++mm) {
      int n = nbase + mm;
      xt[n * 64 + lane] = norm_out[n] * acc[mm];  // coalesced 256B store
    }
  }
}

// ---------------- GEMM2: h1t[n][0:32] = norm_out[n]*(h1[n] @ W2), cols 30,31=0
__global__ __launch_bounds__(TPB) void k_gemm2(const float4* __restrict__ h1_4,
                                               const float* __restrict__ W2,
                                               const float* __restrict__ norm_out,
                                               float* __restrict__ h1t) {
  int lane = threadIdx.x & 63;
  int wid = (blockIdx.x * TPB + threadIdx.x) >> 6;
  int nwaves = gridDim.x * (TPB / 64);
  int gclamp = (lane < NOUTF) ? lane : 0;  // keep loads in-bounds
  float w[64];
#pragma unroll
  for (int k = 0; k < 64; ++k) {
    float wv = W2[k * NOUTF + gclamp];
    w[k] = (lane < NOUTF) ? wv : 0.f;
  }
  int m = lane >> 4, q = lane & 15;
  for (int grp = wid; grp < NN / 4; grp += nwaves) {
    int nbase = grp * 4;
    float4 rv = h1_4[(nbase + m) * 16 + q];
    int r0 = __float_as_int(rv.x), r1 = __float_as_int(rv.y);
    int r2 = __float_as_int(rv.z), r3 = __float_as_int(rv.w);
    float acc[4] = {0.f, 0.f, 0.f, 0.f};
#pragma unroll
    for (int mm = 0; mm < 4; ++mm) {
#pragma unroll
      for (int ql = 0; ql < 16; ++ql) {
        int sl = mm * 16 + ql;
        acc[mm] = fmaf(__int_as_float(__builtin_amdgcn_readlane(r0, sl)), w[ql * 4 + 0], acc[mm]);
        acc[mm] = fmaf(__int_as_float(__builtin_amdgcn_readlane(r1, sl)), w[ql * 4 + 1], acc[mm]);
        acc[mm] = fmaf(__int_as_float(__builtin_amdgcn_readlane(r2, sl)), w[ql * 4 + 2], acc[mm]);
        acc[mm] = fmaf(__int_as_float(__builtin_amdgcn_readlane(r3, sl)), w[ql * 4 + 3], acc[mm]);
      }
    }
    if (lane < 32) {
#pragma unroll
      for (int mm = 0; mm < 4; ++mm) {
        int n = nbase + mm;
        float v = (lane < NOUTF) ? norm_out[n] * acc[mm] : 0.f;
        h1t[n * 32 + lane] = v;  // pad cols 30,31 with zeros
      }
    }
  }
}

// ---------------- AGG1: h1[n] = relu(norm_in[n]*segsum(xt[src]) + b1) -------
// One wave per node; 4 edge-slots x 16 lanes x float4 -> 1KB coalesced gather
// per instruction. 2x unrolled for 2 outstanding gathers.
__global__ __launch_bounds__(TPB) void k_agg1(const float4* __restrict__ xt4,
                                              const int* __restrict__ src_sorted,
                                              const int* __restrict__ row_ptr,
                                              const float* __restrict__ norm_in,
                                              const float* __restrict__ b1,
                                              float4* __restrict__ h1_4) {
  int node = (blockIdx.x * TPB + threadIdx.x) >> 6;
  int lane = threadIdx.x & 63;
  int slot = lane >> 4;  // 0..3
  int fl = lane & 15;    // float4 index: features fl*4..fl*4+3
  int beg = row_ptr[node];
  int end = row_ptr[node + 1];
  float4 a0 = make_float4(0.f, 0.f, 0.f, 0.f);
  float4 a1 = make_float4(0.f, 0.f, 0.f, 0.f);
  int e = beg + slot;
  for (; e + 4 < end; e += 8) {
    int s0 = src_sorted[e];
    int s1 = src_sorted[e + 4];
    float4 v0 = xt4[s0 * 16 + fl];
    float4 v1 = xt4[s1 * 16 + fl];
    a0.x += v0.x; a0.y += v0.y; a0.z += v0.z; a0.w += v0.w;
    a1.x += v1.x; a1.y += v1.y; a1.z += v1.z; a1.w += v1.w;
  }
  if (e < end) {
    int s0 = src_sorted[e];
    float4 v0 = xt4[s0 * 16 + fl];
    a0.x += v0.x; a0.y += v0.y; a0.z += v0.z; a0.w += v0.w;
  }
  a0.x += a1.x; a0.y += a1.y; a0.z += a1.z; a0.w += a1.w;
#pragma unroll
  for (int off = 16; off <= 32; off <<= 1) {
    a0.x += __shfl_xor(a0.x, off);
    a0.y += __shfl_xor(a0.y, off);
    a0.z += __shfl_xor(a0.z, off);
    a0.w += __shfl_xor(a0.w, off);
  }
  if (slot == 0) {
    float ni = norm_in[node];
    float4 b = reinterpret_cast<const float4*>(b1)[fl];
    float4 r;
    r.x = fmaxf(fmaf(a0.x, ni, b.x), 0.f);
    r.y = fmaxf(fmaf(a0.y, ni, b.y), 0.f);
    r.z = fmaxf(fmaf(a0.z, ni, b.z), 0.f);
    r.w = fmaxf(fmaf(a0.w, ni, b.w), 0.f);
    h1_4[node * 16 + fl] = r;
  }
}

// ---------------- AGG2: out[n] = norm_in[n]*segsum(h1t[src]) + b2 -----------
// 32 padded features -> 8 edge-slots x 8 lanes x float4 per wave.
__global__ __launch_bounds__(TPB) void k_agg2(const float4* __restrict__ h1t4,
                                              const int* __restrict__ src_sorted,
                                              const int* __restrict__ row_ptr,
                                              const float* __restrict__ norm_in,
                                              const float* __restrict__ b2,
                                              float* __restrict__ out) {
  int node = (blockIdx.x * TPB + threadIdx.x) >> 6;
  int lane = threadIdx.x & 63;
  int slot = lane >> 3;  // 0..7
  int fl = lane & 7;     // float4 index within 32 padded features
  int beg = row_ptr[node];
  int end = row_ptr[node + 1];
  float4 a0 = make_float4(0.f, 0.f, 0.f, 0.f);
  float4 a1 = make_float4(0.f, 0.f, 0.f, 0.f);
  int e = beg + slot;
  for (; e + 8 < end; e += 16) {
    int s0 = src_sorted[e];
    int s1 = src_sorted[e + 8];
    float4 v0 = h1t4[s0 * 8 + fl];
    float4 v1 = h1t4[s1 * 8 + fl];
    a0.x += v0.x; a0.y += v0.y; a0.z += v0.z; a0.w += v0.w;
    a1.x += v1.x; a1.y += v1.y; a1.z += v1.z; a1.w += v1.w;
  }
  if (e < end) {
    int s0 = src_sorted[e];
    float4 v0 = h1t4[s0 * 8 + fl];
    a0.x += v0.x; a0.y += v0.y; a0.z += v0.z; a0.w += v0.w;
  }
  a0.x += a1.x; a0.y += a1.y; a0.z += a1.z; a0.w += a1.w;
#pragma unroll
  for (int off = 8; off <= 32; off <<= 1) {
    a0.x += __shfl_xor(a0.x, off);
    a0.y += __shfl_xor(a0.y, off);
    a0.z += __shfl_xor(a0.z, off);
    a0.w += __shfl_xor(a0.w, off);
  }
  if (slot == 0) {
    float ni = norm_in[node];
    int f0 = fl * 4;
    float vals[4] = {a0.x, a0.y, a0.z, a0.w};
#pragma unroll
    for (int c = 0; c < 4; ++c) {
      int f = f0 + c;
      if (f < NOUTF) out[node * NOUTF + f] = fmaf(vals[c], ni, b2[f]);
    }
  }
}

extern "C" void kernel_launch(void* const* d_in, const int* in_sizes, int n_in,
                              void* d_out, int out_size, void* d_ws, size_t ws_size,
                              hipStream_t stream) {
  (void)in_sizes; (void)n_in; (void)out_size; (void)ws_size;
  const float* x = (const float*)d_in[0];
  const int* src = (const int*)d_in[1];
  const int* dst = (const int*)d_in[2];
  const float* W1 = (const float*)d_in[3];
  const float* b1 = (const float*)d_in[4];
  const float* W2 = (const float*)d_in[5];
  const float* b2 = (const float*)d_in[6];
  float* out = (float*)d_out;

  // Workspace layout (bytes), total 66,400,640 — all 16B-aligned:
  char* ws = (char*)d_ws;
  int* deg_out = (int*)(ws + 0);              //   400,000
  int* deg_in = (int*)(ws + 400000);          //   400,000
  int* cursor = (int*)(ws + 800000);          //   400,000  (memset with above)
  int* row_ptr = (int*)(ws + 1200000);        //   400,128 (100001 ints, padded)
  int* bsums = (int*)(ws + 1600128);          //       512
  float* norm_out = (float*)(ws + 1600640);   //   400,000
  float* norm_in = (float*)(ws + 2000640);    //   400,000
  int* src_sorted = (int*)(ws + 2400640);     // 12,800,000
  float* xt = (float*)(ws + 15200640);        // 25,600,000 (reused as h1t later)
  float* h1 = (float*)(ws + 40800640);        // 25,600,000
  float* h1t = xt;  // xt is dead after k_agg1; h1t needs only 12.8 MB

  hipMemsetAsync(ws, 0, 1200000, stream);  // deg_out, deg_in, cursor
  k_deg<<<NE / TPB, TPB, 0, stream>>>(src, dst, deg_out, deg_in);
  k_scan1<<<NSCAN, TPB, 0, stream>>>(deg_in, bsums);
  k_scan2<<<1, 128, 0, stream>>>(bsums);
  k_scan3<<<NSCAN, TPB, 0, stream>>>(deg_in, bsums, row_ptr);
  k_norm<<<(NN + TPB - 1) / TPB, TPB, 0, stream>>>(deg_out, deg_in, norm_out, norm_in);
  k_bucket<<<NE / TPB, TPB, 0, stream>>>(src, dst, row_ptr, cursor, src_sorted);
  k_gemm1<<<1024, TPB, 0, stream>>>((const float4*)x, W1, norm_out, xt);
  k_agg1<<<NN / 4, TPB, 0, stream>>>((const float4*)xt, src_sorted, row_ptr, norm_in, b1, (float4*)h1);
  k_gemm2<<<1024, TPB, 0, stream>>>((const float4*)h1, W2, norm_out, h1t);
  k_agg2<<<NN / 4, TPB, 0, stream>>>((const float4*)h1t, src_sorted, row_ptr, norm_in, b2, out);
}